// Round 13
// baseline (11182.844 us; speedup 1.0000x reference)
//
#include <hip/hip_runtime.h>
#include <hip/hip_bf16.h>
#include <stdint.h>

typedef __hip_bfloat16 bf16;
typedef __attribute__((ext_vector_type(8))) short bf16x8;
typedef __attribute__((ext_vector_type(4))) float f32x4;
typedef __attribute__((ext_vector_type(8))) unsigned short us8;

#define NB 8192
#define NE 256
#define NH 1024

__device__ __forceinline__ float bf2f(unsigned short u) {
  union { unsigned int i; float f; } x; x.i = ((unsigned int)u) << 16; return x.f;
}
__device__ __forceinline__ float sigm(float x) {
  return __builtin_amdgcn_rcpf(1.f + __expf(-x));
}
__device__ __forceinline__ float tanh_f(float x) {
  return 1.f - 2.f * __builtin_amdgcn_rcpf(1.f + __expf(2.f * x));
}

#define BAR() __builtin_amdgcn_s_barrier()
#define FENCE() asm volatile("" ::: "memory")
#define LGKME() asm volatile("s_waitcnt lgkmcnt(0)" ::: "memory")

// 32-MFMA cluster (no setprio: r12-validated)
#define MFMA32(MH)                                                            \
  do {                                                                        \
    _Pragma("unroll") for (int i_ = 0; i_ < 4; ++i_)                          \
      _Pragma("unroll") for (int g_ = 0; g_ < 4; ++g_) {                      \
        acc[(MH)*4 + i_][g_] = __builtin_amdgcn_mfma_f32_16x16x32_bf16(       \
            af[i_], bv[g_], acc[(MH)*4 + i_][g_], 0, 0, 0);                   \
        acc[(MH)*4 + i_][g_] = __builtin_amdgcn_mfma_f32_16x16x32_bf16(       \
            af[4 + i_], bv[4 + g_], acc[(MH)*4 + i_][g_], 0, 0, 0);           \
      }                                                                       \
  } while (0)

// A-fragments DIRECT from global (L2-resident panel): 4 m-frags x 2 k-slices.
// Lane l reads row (..+l15), 16B chunk at col (l>>4)*8 (+32 for slice 1):
// per row the two slices cover 128B contiguous -> full-line L2 sectors.
#define LDAG(MH, KLOC)                                                        \
  do {                                                                        \
    const bf16* ab_ = asec + (KLOC);                                          \
    _Pragma("unroll") for (int i_ = 0; i_ < 4; ++i_) {                        \
      af[i_]     = *(const bf16x8*)(ab_ + oa[MH][i_]);                        \
      af[4 + i_] = *(const bf16x8*)(ab_ + oa[MH][i_] + 32);                   \
    }                                                                         \
  } while (0)

// ds_read B-frags: 4 gates, both k-slices (XOR-swizzled; unchanged layout)
#define LDB8(BUF)                                                             \
  do {                                                                        \
    const char* Bb_ = Barena + (BUF)*32768;                                   \
    _Pragma("unroll") for (int g_ = 0; g_ < 4; ++g_) {                        \
      int ro_ = (g_ * 64 + nc * 16 + l15) * 128;                              \
      bv[g_]     = *(const bf16x8*)(Bb_ + ro_ + co0);                         \
      bv[4 + g_] = *(const bf16x8*)(Bb_ + ro_ + co1);                         \
    }                                                                         \
  } while (0)

struct CellP {
  const bf16* X; const bf16* Hin;
  const bf16* Wih; const bf16* Whh;
  const float* bias; float* Cst; bf16* Hout;
  int ldx, Kx, Kh, czero;
};

// ---- fused GEMM + LSTM cell, 256x256: A direct-from-L2, B reg-staged LDS ---
// gates = X@Wih^T + Hin@Whh^T + bias ; c' = sig(f)*c + sig(i)*tanh(g); h = sig(o)*tanh(c')
// 8 waves (2M x 4N), wave = 128x64. LDS = Bs only (64KB dbuf).
// Rationale (r12 post-mortem): kernel was LDS-BW-bound 5:1 (192KB read +
// 64KB write per tile vs 620cyc MFMA). A (2/3 of reads) moves to L2 (panel is
// L2-resident via m-major XCD mapping); B staging via T14 reg-stage
// (global->reg Ph1/Ph3, ds_write Ph2/Ph4, published by LGKME+BAR). No manual
// vmcnt anywhere: compiler tracks af/breg loads; ds_writes drain via lgkm.
__global__ __launch_bounds__(512, 2) void k_cell(CellP PA, CellP PB, int nA)
{
  __shared__ bf16 Bs[2][256][64];
  char* Barena = (char*)&Bs[0][0][0];

  const CellP p = (blockIdx.x < (unsigned)nA) ? PA : PB;
  const int bid = (blockIdx.x < (unsigned)nA) ? blockIdx.x : (blockIdx.x - nA);

  const int tid = threadIdx.x;
  const int l = tid & 63;
  const int l15 = l & 15;
  const int wv = tid >> 6;
  const int wr = wv >> 2;
  const int nc = wv & 3;

  // m-major XCD ownership: XCD x owns m-tiles {4x..4x+3} x all hc (L2-fit A).
  const int xcd = bid & 7, j = bid >> 3;
  const int m0 = (xcd * 4 + (j & 3)) * 256;
  const int hc0 = (j >> 2) * 64;

  const int NTt = (p.Kx + p.Kh) >> 6;   // total K-tiles of 64
  const int TX = p.Kx >> 7;             // iters (2 tiles each) in X section
  const int TH = p.Kh >> 7;

  // read-side swizzled chunk byte offsets for k-slices 0,1
  const int co0 = (((l >> 4) + 0) ^ (l & 7)) * 16;
  const int co1 = (((l >> 4) + 4) ^ (l & 7)) * 16;

  // B reg-staging: write w covers LDS row roww = w*64 + (tid>>3), global
  // chunk cg = tid&7; content rule LDS[row][c] = global[row][c^(row&7)].
  const int row_t = tid >> 3;
  const int cg = tid & 7;
  int wadr[4];
#pragma unroll
  for (int w = 0; w < 4; ++w) {
    int row = w * 64 + row_t;
    wadr[w] = row * 128 + ((cg ^ (row & 7)) << 4);
  }

  // B global reg-load for tile kt (4 x 16B per thread, coalesced rows)
  auto bloadg = [&](int kt, f32x4* br) {
    int kc = kt << 6;
    const bf16* src; int ldb;
    if (kc < p.Kx) { src = p.Wih + kc; ldb = p.Kx; }
    else           { src = p.Whh + (kc - p.Kx); ldb = NH; }
#pragma unroll
    for (int w = 0; w < 4; ++w) {
      int row = w * 64 + row_t;                       // 0..255 = gate*64+hcrow
      int grow = (row >> 6) * NH + hc0 + (row & 63);  // global W row
      br[w] = *(const f32x4*)(src + (unsigned)(grow * ldb + cg * 8));
    }
  };
  auto bwrite = [&](int buf, const f32x4* br) {
#pragma unroll
    for (int w = 0; w < 4; ++w)
      *(f32x4*)(Barena + buf * 32768 + wadr[w]) = br[w];
  };

  f32x4 acc[8][4];
  f32x4 zero4 = {0.f, 0.f, 0.f, 0.f};
#pragma unroll
  for (int i = 0; i < 8; ++i)
#pragma unroll
    for (int j2 = 0; j2 < 4; ++j2) acc[i][j2] = zero4;

  // prologue: B tile0 -> regs -> LDS buf0; publish.
  {
    f32x4 br[4];
    bloadg(0, br);
    bwrite(0, br);
  }
  LGKME();
  BAR();

  // one section = contiguous K range with fixed A source/ld (X or H)
  auto run_section = [&](const bf16* asec, int ald, int koff, int t0, int tcnt) {
    if (tcnt == 0) return;
    unsigned oa[2][4];
#pragma unroll
    for (int mh_ = 0; mh_ < 2; ++mh_)
#pragma unroll
      for (int i_ = 0; i_ < 4; ++i_)
        oa[mh_][i_] = (unsigned)((m0 + wr * 128 + mh_ * 64 + i_ * 16 + l15) * ald +
                                 ((l >> 4) << 3));
    bf16x8 af[8], bv[8];
    for (int t = t0; t < t0 + tcnt; ++t) {
      const int kt0 = 2 * t;
      const int kloc0 = (kt0 << 6) - koff;
      const bool more = (kt0 + 2 < NTt);
      f32x4 br[4];

      // Ph1: compute b0.mh0 ; load B(kt0+1) -> regs
      bloadg(kt0 + 1, br);
      LDB8(0);
      LDAG(0, kloc0);
      FENCE(); BAR();
      MFMA32(0);
      LGKME();
      BAR();

      // Ph2: compute b0.mh1 ; ds_write B(kt0+1) -> Bs[1]
      bwrite(1, br);
      LDAG(1, kloc0);
      FENCE(); BAR();
      MFMA32(1);
      LGKME();          // drains ds_writes -> Bs[1] published at BAR
      BAR();

      // Ph3: compute b1.mh0 ; load B(kt0+2) -> regs
      if (more) bloadg(kt0 + 2, br);
      LDB8(1);
      LDAG(0, kloc0 + 64);
      FENCE(); BAR();
      MFMA32(0);
      LGKME();
      BAR();

      // Ph4: compute b1.mh1 ; ds_write B(kt0+2) -> Bs[0]
      if (more) bwrite(0, br);
      LDAG(1, kloc0 + 64);
      FENCE(); BAR();
      MFMA32(1);
      LGKME();          // publishes Bs[0] at BAR
      BAR();
    }
  };

  run_section(p.X, p.ldx, 0, 0, TX);
  run_section(p.Hin, NH, p.Kx, TX, TH);

  // epilogue: acc[m][gate][r]; C/D layout col=lane&15, row=(lane>>4)*4+r
  const int ecol = hc0 + nc * 16 + l15;
  const float bi = p.bias[ecol];
  const float bff = p.bias[NH + ecol];
  const float bg = p.bias[2 * NH + ecol];
  const float bo = p.bias[3 * NH + ecol];
  const int r0 = m0 + wr * 128 + ((l >> 4) << 2);
#pragma unroll
  for (int m = 0; m < 8; ++m) {
#pragma unroll
    for (int r = 0; r < 4; ++r) {
      int row = r0 + m * 16 + r;
      unsigned idx = (unsigned)(row * NH) + ecol;
      float gi = sigm(acc[m][0][r] + bi);
      float gf = sigm(acc[m][1][r] + bff);
      float gg = tanh_f(acc[m][2][r] + bg);
      float go = sigm(acc[m][3][r] + bo);
      float cold = p.czero ? 0.f : p.Cst[idx];
      float cn = gf * cold + gi * gg;
      p.Cst[idx] = cn;
      p.Hout[idx] = __float2bfloat16(go * tanh_f(cn));
    }
  }
}

// ---------------- MLP decode head + displacement add + re-embed ----------------
__global__ __launch_bounds__(256) void k_mlp(
    const bf16* __restrict__ h1, const bf16* __restrict__ W1b, const float* __restrict__ b1,
    const float* __restrict__ W2, const float* __restrict__ b2,
    const float* __restrict__ W3, const float* __restrict__ b3,
    const float* __restrict__ cin, float* __restrict__ cout,
    float* __restrict__ preds, const float* __restrict__ Wemb,
    const float* __restrict__ bemb, bf16* __restrict__ embout)
{
  const int l = threadIdx.x & 63;
  const int row = blockIdx.x * 4 + (threadIdx.x >> 6);

  const us8* hp = (const us8*)(h1 + (size_t)row * NH + l * 16);
  us8 hv0 = hp[0], hv1 = hp[1];
  float h[16];
#pragma unroll
  for (int j = 0; j < 8; ++j) { h[j] = bf2f(hv0[j]); h[8 + j] = bf2f(hv1[j]); }

  float y1[32];
#pragma unroll
  for (int j = 0; j < 32; ++j) {
    const us8* wp = (const us8*)(W1b + (size_t)j * NH + l * 16);
    us8 w0 = wp[0], w1 = wp[1];
    float d = 0.f;
#pragma unroll
    for (int k = 0; k < 8; ++k) {
      d = fmaf(h[k], bf2f(w0[k]), d);
      d = fmaf(h[8 + k], bf2f(w1[k]), d);
    }
#pragma unroll
    for (int off2 = 32; off2 > 0; off2 >>= 1) d += __shfl_xor(d, off2);
    y1[j] = fmaxf(d + b1[j], 0.f);
  }

  float y2[16];
#pragma unroll
  for (int m = 0; m < 16; ++m) {
    float s = b2[m];
#pragma unroll
    for (int j = 0; j < 32; ++j) s = fmaf(W2[m * 32 + j], y1[j], s);
    y2[m] = fmaxf(s, 0.f);
  }
  float o0 = b3[0], o1 = b3[1];
#pragma unroll
  for (int k = 0; k < 16; ++k) {
    o0 = fmaf(W3[k], y2[k], o0);
    o1 = fmaf(W3[16 + k], y2[k], o1);
  }
  float n0 = cin[row * 2] + o0;
  float n1 = cin[row * 2 + 1] + o1;
  if (l == 0) {
    preds[row * 2] = n0; preds[row * 2 + 1] = n1;
    cout[row * 2] = n0;  cout[row * 2 + 1] = n1;
  }
#pragma unroll
  for (int q = 0; q < 4; ++q) {
    int e = l + q * 64;
    float v = fmaf(n0, Wemb[e * 2], fmaf(n1, Wemb[e * 2 + 1], bemb[e]));
    embout[(size_t)row * NE + e] = __float2bfloat16(fmaxf(v, 0.f));
  }
}

// ---------------- embedding of observed trajectory (all 8 steps) ----------------
__global__ void k_embed(const float* __restrict__ x, const float* __restrict__ W,
                        const float* __restrict__ b, bf16* __restrict__ out) {
  const int l = threadIdx.x & 63;
  const int row = (blockIdx.x * 256 + threadIdx.x) >> 6;
  float x0 = x[row * 2], x1 = x[row * 2 + 1];
#pragma unroll
  for (int q = 0; q < 4; ++q) {
    int e = l + q * 64;
    float v = fmaf(x0, W[e * 2], fmaf(x1, W[e * 2 + 1], b[e]));
    out[(size_t)row * NE + e] = __float2bfloat16(fmaxf(v, 0.f));
  }
}

__global__ void k_f2b(const float* __restrict__ in, bf16* __restrict__ out, int n) {
  int i = (blockIdx.x * 256 + threadIdx.x) * 4;
  if (i >= n) return;
  float4 v = *(const float4*)(in + i);
  out[i] = __float2bfloat16(v.x);
  out[i + 1] = __float2bfloat16(v.y);
  out[i + 2] = __float2bfloat16(v.z);
  out[i + 3] = __float2bfloat16(v.w);
}

__global__ void k_badd(const float* __restrict__ a, const float* __restrict__ b,
                       float* __restrict__ o, int n) {
  int i = blockIdx.x * 256 + threadIdx.x;
  if (i < n) o[i] = a[i] + b[i];
}

extern "C" void kernel_launch(void* const* d_in, const int* in_sizes, int n_in,
                              void* d_out, int out_size, void* d_ws, size_t ws_size,
                              hipStream_t stream) {
  const float* obs   = (const float*)d_in[0];
  const float* Wemb  = (const float*)d_in[1];
  const float* bemb  = (const float*)d_in[2];
  const float* Wih0f = (const float*)d_in[3];
  const float* Whh0f = (const float*)d_in[4];
  const float* bih0  = (const float*)d_in[5];
  const float* bhh0  = (const float*)d_in[6];
  const float* Wih1f = (const float*)d_in[7];
  const float* Whh1f = (const float*)d_in[8];
  const float* bih1  = (const float*)d_in[9];
  const float* bhh1  = (const float*)d_in[10];
  const float* W1f   = (const float*)d_in[11];
  const float* b1m   = (const float*)d_in[12];
  const float* W2    = (const float*)d_in[13];
  const float* b2    = (const float*)d_in[14];
  const float* W3    = (const float*)d_in[15];
  const float* b3    = (const float*)d_in[16];

  char* ws = (char*)d_ws;
  size_t off = 0;
  auto alloc = [&](size_t bytes) -> void* {
    void* p = ws + off;
    off += (bytes + 255) & ~(size_t)255;
    return p;
  };
  bf16* wih0 = (bf16*)alloc((size_t)4096 * 256 * 2);
  bf16* whh0 = (bf16*)alloc((size_t)4096 * 1024 * 2);
  bf16* wih1 = (bf16*)alloc((size_t)4096 * 1024 * 2);
  bf16* whh1 = (bf16*)alloc((size_t)4096 * 1024 * 2);
  bf16* w1b  = (bf16*)alloc((size_t)32 * 1024 * 2);
  float* b0c = (float*)alloc((size_t)4096 * 4);
  float* b1c = (float*)alloc((size_t)4096 * 4);
  bf16* emb  = (bf16*)alloc((size_t)8 * NB * NE * 2);
  bf16* h0a  = (bf16*)alloc((size_t)NB * NH * 2);
  bf16* h0b  = (bf16*)alloc((size_t)NB * NH * 2);
  bf16* h1a  = (bf16*)alloc((size_t)NB * NH * 2);
  bf16* h1b  = (bf16*)alloc((size_t)NB * NH * 2);
  float* c0  = (float*)alloc((size_t)NB * NH * 4);
  float* c1  = (float*)alloc((size_t)NB * NH * 4);
  float* curr = (float*)alloc((size_t)NB * 2 * 4);
  bf16* cemb = (bf16*)alloc((size_t)NB * NE * 2);

  k_f2b<<<1024, 256, 0, stream>>>(Wih0f, wih0, 4096 * 256);
  k_f2b<<<4096, 256, 0, stream>>>(Whh0f, whh0, 4096 * 1024);
  k_f2b<<<4096, 256, 0, stream>>>(Wih1f, wih1, 4096 * 1024);
  k_f2b<<<4096, 256, 0, stream>>>(Whh1f, whh1, 4096 * 1024);
  k_f2b<<<32, 256, 0, stream>>>(W1f, w1b, 32 * 1024);
  k_badd<<<16, 256, 0, stream>>>(bih0, bhh0, b0c, 4096);
  k_badd<<<16, 256, 0, stream>>>(bih1, bhh1, b1c, 4096);
  k_embed<<<(8 * NB) / 4, 256, 0, stream>>>(obs, Wemb, bemb, emb);

  bf16* h0buf[2] = {h0a, h0b};
  bf16* h1buf[2] = {h1a, h1b};
  float* preds = (float*)d_out;

  auto mk = [&](const bf16* X, int ldx, int Kx, const bf16* Hin, int Kh,
                const bf16* Wih, const bf16* Whh, const float* bb, float* C,
                bf16* Ho, int cz) {
    CellP q;
    q.X = X; q.Hin = Hin; q.Wih = Wih; q.Whh = Whh;
    q.bias = bb; q.Cst = C; q.Hout = Ho;
    q.ldx = ldx; q.Kx = Kx; q.Kh = Kh; q.czero = cz;
    return q;
  };

  // L0(0): encode step 0, h/c start at zero (Kh=0 -> Hin never read)
  {
    CellP p0 = mk(emb, NE, NE, h0buf[1], 0, wih0, whh0, b0c, c0, h0buf[0], 1);
    k_cell<<<512, 512, 0, stream>>>(p0, p0, 512);
  }
  // encode: fused L1(t) || L0(t+1), t = 0..7 (both depend only on h0(t))
  for (int t = 0; t < 8; ++t) {
    int cu = t & 1, pv = cu ^ 1;
    int kh1 = (t == 0) ? 0 : NH;
    CellP pl1 = mk(h0buf[cu], NH, NH, h1buf[pv], kh1,
                   wih1, whh1, b1c, c1, h1buf[cu], t == 0);
    const bf16* xnext = (t + 1 < 8) ? emb + (size_t)(t + 1) * NB * NE
                                    : emb + (size_t)7 * NB * NE;  // t+1==8: embed(obs[-1])
    CellP pl0 = mk(xnext, NE, NE, h0buf[cu], NH,
                   wih0, whh0, b0c, c0, h0buf[pv], 0);
    k_cell<<<1024, 512, 0, stream>>>(pl1, pl0, 512);
  }
  // decode: serial (L0 input comes from k_mlp of previous step)
  for (int t = 8; t < 20; ++t) {
    int cu = t & 1, pv = cu ^ 1;
    if (t > 8) {
      CellP pl0 = mk(cemb, NE, NE, h0buf[pv], NH,
                     wih0, whh0, b0c, c0, h0buf[cu], 0);
      k_cell<<<512, 512, 0, stream>>>(pl0, pl0, 512);
    }
    CellP pl1 = mk(h0buf[cu], NH, NH, h1buf[pv], NH,
                   wih1, whh1, b1c, c1, h1buf[cu], 0);
    k_cell<<<512, 512, 0, stream>>>(pl1, pl1, 512);
    int pI = t - 8;
    const float* cin = (pI == 0) ? (obs + (size_t)7 * NB * 2) : curr;
    k_mlp<<<NB / 4, 256, 0, stream>>>(h1buf[cu], w1b, b1m, W2, b2, W3, b3,
                                      cin, curr, preds + (size_t)pI * NB * 2,
                                      Wemb, bemb, cemb);
  }
}

// Round 14
// 4624.194 us; speedup vs baseline: 2.4183x; 2.4183x over previous
//
#include <hip/hip_runtime.h>
#include <hip/hip_bf16.h>
#include <stdint.h>

typedef __hip_bfloat16 bf16;
typedef __attribute__((ext_vector_type(8))) short bf16x8;
typedef __attribute__((ext_vector_type(4))) float f32x4;
typedef __attribute__((ext_vector_type(8))) unsigned short us8;

#define NB 8192
#define NE 256
#define NH 1024

__device__ __forceinline__ float bf2f(unsigned short u) {
  union { unsigned int i; float f; } x; x.i = ((unsigned int)u) << 16; return x.f;
}
__device__ __forceinline__ float sigm(float x) {
  return __builtin_amdgcn_rcpf(1.f + __expf(-x));
}
__device__ __forceinline__ float tanh_f(float x) {
  return 1.f - 2.f * __builtin_amdgcn_rcpf(1.f + __expf(2.f * x));
}

#define BAR() __builtin_amdgcn_s_barrier()
#define FENCE() asm volatile("" ::: "memory")
#define LGKME() asm volatile("s_waitcnt lgkmcnt(0)" ::: "memory")
#define VMW(N) asm volatile("s_waitcnt vmcnt(" #N ")" ::: "memory")

#define GLDS(G, S)                                                            \
  __builtin_amdgcn_global_load_lds(                                           \
      (const __attribute__((address_space(1))) void*)(G),                     \
      (__attribute__((address_space(3))) void*)(S), 16, 0, 0)

// 32-MFMA cluster (no setprio: r12-validated)
#define MFMA32(MH)                                                            \
  do {                                                                        \
    _Pragma("unroll") for (int i_ = 0; i_ < 4; ++i_)                          \
      _Pragma("unroll") for (int g_ = 0; g_ < 4; ++g_) {                      \
        acc[(MH)*4 + i_][g_] = __builtin_amdgcn_mfma_f32_16x16x32_bf16(       \
            af[i_], bv[g_], acc[(MH)*4 + i_][g_], 0, 0, 0);                   \
        acc[(MH)*4 + i_][g_] = __builtin_amdgcn_mfma_f32_16x16x32_bf16(       \
            af[4 + i_], bv[4 + g_], acc[(MH)*4 + i_][g_], 0, 0, 0);           \
      }                                                                       \
  } while (0)

// ds_read A-frags: 4 m-frags of m-half MH, both k-slices (XOR-swizzled)
#define LDA8(BUF, MH)                                                         \
  do {                                                                        \
    const char* Ab_ = (const char*)&As[BUF][0][0];                            \
    _Pragma("unroll") for (int i_ = 0; i_ < 4; ++i_) {                        \
      int ro_ = (wr * 128 + (MH)*64 + i_ * 16 + l15) * 128;                   \
      af[i_]     = *(const bf16x8*)(Ab_ + ro_ + co0);                         \
      af[4 + i_] = *(const bf16x8*)(Ab_ + ro_ + co1);                         \
    }                                                                         \
  } while (0)

// ds_read B-frags: 4 gates, both k-slices
#define LDB8(BUF)                                                             \
  do {                                                                        \
    const char* Bb_ = (const char*)&Bs[BUF][0][0];                            \
    _Pragma("unroll") for (int g_ = 0; g_ < 4; ++g_) {                        \
      int ro_ = (g_ * 64 + nc * 16 + l15) * 128;                              \
      bv[g_]     = *(const bf16x8*)(Bb_ + ro_ + co0);                         \
      bv[4 + g_] = *(const bf16x8*)(Bb_ + ro_ + co1);                         \
    }                                                                         \
  } while (0)

struct CellP {
  const bf16* X; const bf16* Hin;
  const bf16* Wih; const bf16* Whh;
  const float* bias; float* Cst; bf16* Hout;
  int ldx, Kx, Kh, czero;
};

// -------- fused GEMM + LSTM cell, 256x256, 4-phase/iter (r12 champion) ------
// gates = X@Wih^T + Hin@Whh^T + bias ; c' = sig(f)*c + sig(i)*tanh(g); h = sig(o)*tanh(c')
// Block: 256 M-rows x (64 hcols x 4 gates). 8 waves (2M x 4N), wave = 128x64.
// Phase: {ds_read; stage; BAR; MFMA; lgkmcnt(0); (VMW); BAR}.
// r14 change: staging address streams hoisted to 16 base pointers (one mul
// each, once); per-GLDS = uniform source-select + add (VALU cut, r12 post-
// mortem: addr mul-chains were the main VALUBusy consumer).
__global__ __launch_bounds__(512, 2) void k_cell(CellP PA, CellP PB, int nA)
{
  __shared__ bf16 As[2][256][64];
  __shared__ bf16 Bs[2][256][64];

  const CellP p = (blockIdx.x < (unsigned)nA) ? PA : PB;
  const int bid = (blockIdx.x < (unsigned)nA) ? blockIdx.x : (blockIdx.x - nA);

  const int tid = threadIdx.x;
  const int l = tid & 63;
  const int l15 = l & 15;
  const int wv = tid >> 6;
  const int wr = wv >> 2;
  const int nc = wv & 3;

  // m-major XCD ownership: XCD x owns m-tiles {4x..4x+3} x all hc (L2-fit A).
  const int xcd = bid & 7, j = bid >> 3;
  const int m0 = (xcd * 4 + (j & 3)) * 256;
  const int hc0 = (j >> 2) * 64;

  const int NT = (p.Kx + p.Kh) >> 6;
  const int T = NT >> 1;
  const int Kx = p.Kx;

  const int rowid = tid >> 3;
  const int ch8 = ((tid & 7) ^ (rowid & 7)) * 8;
  const int wv8 = wv * 8;

  const int co0 = (((l >> 4) + 0) ^ (l & 7)) * 16;
  const int co1 = (((l >> 4) + 4) ^ (l & 7)) * 16;

  // ---- hoisted stage base pointers: addr(kt) = base + (kt*64 [- Kx]) ----
  // A streams idx = half*2+rnd -> tile row tr = rnd*128 + half*64
  const bf16* baseAX[4];
  const bf16* baseAH[4];
#pragma unroll
  for (int idx = 0; idx < 4; ++idx) {
    int tr = (idx & 1) * 128 + (idx >> 1) * 64;
    int row = m0 + tr + rowid;
    baseAX[idx] = p.X + (unsigned)(row * p.ldx + ch8);
    baseAH[idx] = p.Hin + (unsigned)(row * NH + ch8);
  }
  // B streams idx = gate
  const bf16* baseBX[4];
  const bf16* baseBH[4];
#pragma unroll
  for (int g = 0; g < 4; ++g) {
    int grow = g * NH + hc0 + rowid;
    baseBX[g] = p.Wih + (unsigned)(grow * Kx + ch8);
    baseBH[g] = p.Whh + (unsigned)(grow * NH + ch8);
  }

  f32x4 acc[8][4];
  f32x4 zero4 = {0.f, 0.f, 0.f, 0.f};
#pragma unroll
  for (int i = 0; i < 8; ++i)
#pragma unroll
    for (int j2 = 0; j2 < 4; ++j2) acc[i][j2] = zero4;

  auto stage_a = [&](int buf, int half, int kt) {
    int kc = kt << 6;
    bool inX = (kc < Kx);
    int koff = inX ? kc : (kc - Kx);
#pragma unroll
    for (int rnd = 0; rnd < 2; ++rnd) {
      int idx = half * 2 + rnd;
      const bf16* gp = (inX ? baseAX[idx] : baseAH[idx]) + koff;
      GLDS(gp, &As[buf][rnd * 128 + half * 64 + wv8][0]);
    }
  };
  auto stage_b = [&](int buf, int half, int kt) {
    int kc = kt << 6;
    bool inX = (kc < Kx);
    int koff = inX ? kc : (kc - Kx);
#pragma unroll
    for (int rnd = 0; rnd < 2; ++rnd) {
      int gate = rnd * 2 + half;
      const bf16* gp = (inX ? baseBX[gate] : baseBH[gate]) + koff;
      GLDS(gp, &Bs[buf][gate * 64 + wv8][0]);
    }
  };

  // prologue: full b0(kt0) + A1.h0(kt1)
  stage_a(0, 0, 0);
  stage_a(0, 1, 0);
  stage_b(0, 0, 0);
  stage_b(0, 1, 0);
  stage_a(1, 0, 1);
  VMW(2);
  BAR();

  for (int t = 0; t < T; ++t) {
    const int kt1 = 2 * t + 1;
    const bool last = (t == T - 1);
    bf16x8 af[8], bv[8];

    // Ph1: compute b0.mh0 ; stage A1.h1 + B1 (kt1)
    LDB8(0); LDA8(0, 0);
    stage_a(1, 1, kt1);
    stage_b(1, 0, kt1);
    stage_b(1, 1, kt1);
    FENCE(); BAR();
    MFMA32(0);
    LGKME();
    BAR();

    // Ph2: compute b0.mh1 ; stage A0.h0 (kt0+2)
    LDA8(0, 1);
    if (!last) stage_a(0, 0, kt1 + 1);
    FENCE(); BAR();
    MFMA32(1);
    LGKME();
    if (last) { VMW(0); } else { VMW(2); }  // complete b1(kt1); leave A0.h0
    BAR();

    // Ph3: compute b1.mh0 ; stage A0.h1 + B0 (kt0+2)
    LDB8(1); LDA8(1, 0);
    if (!last) {
      stage_a(0, 1, kt1 + 1);
      stage_b(0, 0, kt1 + 1);
      stage_b(0, 1, kt1 + 1);
    }
    FENCE(); BAR();
    MFMA32(0);
    LGKME();
    BAR();

    // Ph4: compute b1.mh1 ; stage A1.h0 (kt1+2)
    LDA8(1, 1);
    if (!last) stage_a(1, 0, kt1 + 2);
    FENCE(); BAR();
    MFMA32(1);
    LGKME();
    if (!last) { VMW(2); }  // complete b0(kt0+2); leave A1.h0(kt1+2)
    BAR();
  }

  // epilogue: acc[m][gate][r]; C/D layout col=lane&15, row=(lane>>4)*4+r
  const int ecol = hc0 + nc * 16 + l15;
  const float bi = p.bias[ecol];
  const float bff = p.bias[NH + ecol];
  const float bg = p.bias[2 * NH + ecol];
  const float bo = p.bias[3 * NH + ecol];
  const int r0 = m0 + wr * 128 + ((l >> 4) << 2);
#pragma unroll
  for (int m = 0; m < 8; ++m) {
#pragma unroll
    for (int r = 0; r < 4; ++r) {
      int row = r0 + m * 16 + r;
      unsigned idx = (unsigned)(row * NH) + ecol;
      float gi = sigm(acc[m][0][r] + bi);
      float gf = sigm(acc[m][1][r] + bff);
      float gg = tanh_f(acc[m][2][r] + bg);
      float go = sigm(acc[m][3][r] + bo);
      float cold = p.czero ? 0.f : p.Cst[idx];
      float cn = gf * cold + gi * gg;
      p.Cst[idx] = cn;
      p.Hout[idx] = __float2bfloat16(go * tanh_f(cn));
    }
  }
}

// ---------------- MLP decode head + displacement add + re-embed ----------------
__global__ __launch_bounds__(256) void k_mlp(
    const bf16* __restrict__ h1, const bf16* __restrict__ W1b, const float* __restrict__ b1,
    const float* __restrict__ W2, const float* __restrict__ b2,
    const float* __restrict__ W3, const float* __restrict__ b3,
    const float* __restrict__ cin, float* __restrict__ cout,
    float* __restrict__ preds, const float* __restrict__ Wemb,
    const float* __restrict__ bemb, bf16* __restrict__ embout)
{
  const int l = threadIdx.x & 63;
  const int row = blockIdx.x * 4 + (threadIdx.x >> 6);

  const us8* hp = (const us8*)(h1 + (size_t)row * NH + l * 16);
  us8 hv0 = hp[0], hv1 = hp[1];
  float h[16];
#pragma unroll
  for (int j = 0; j < 8; ++j) { h[j] = bf2f(hv0[j]); h[8 + j] = bf2f(hv1[j]); }

  float y1[32];
#pragma unroll
  for (int j = 0; j < 32; ++j) {
    const us8* wp = (const us8*)(W1b + (size_t)j * NH + l * 16);
    us8 w0 = wp[0], w1 = wp[1];
    float d = 0.f;
#pragma unroll
    for (int k = 0; k < 8; ++k) {
      d = fmaf(h[k], bf2f(w0[k]), d);
      d = fmaf(h[8 + k], bf2f(w1[k]), d);
    }
#pragma unroll
    for (int off2 = 32; off2 > 0; off2 >>= 1) d += __shfl_xor(d, off2);
    y1[j] = fmaxf(d + b1[j], 0.f);
  }

  float y2[16];
#pragma unroll
  for (int m = 0; m < 16; ++m) {
    float s = b2[m];
#pragma unroll
    for (int j = 0; j < 32; ++j) s = fmaf(W2[m * 32 + j], y1[j], s);
    y2[m] = fmaxf(s, 0.f);
  }
  float o0 = b3[0], o1 = b3[1];
#pragma unroll
  for (int k = 0; k < 16; ++k) {
    o0 = fmaf(W3[k], y2[k], o0);
    o1 = fmaf(W3[16 + k], y2[k], o1);
  }
  float n0 = cin[row * 2] + o0;
  float n1 = cin[row * 2 + 1] + o1;
  if (l == 0) {
    preds[row * 2] = n0; preds[row * 2 + 1] = n1;
    cout[row * 2] = n0;  cout[row * 2 + 1] = n1;
  }
#pragma unroll
  for (int q = 0; q < 4; ++q) {
    int e = l + q * 64;
    float v = fmaf(n0, Wemb[e * 2], fmaf(n1, Wemb[e * 2 + 1], bemb[e]));
    embout[(size_t)row * NE + e] = __float2bfloat16(fmaxf(v, 0.f));
  }
}

// ---------------- embedding of observed trajectory (all 8 steps) ----------------
__global__ void k_embed(const float* __restrict__ x, const float* __restrict__ W,
                        const float* __restrict__ b, bf16* __restrict__ out) {
  const int l = threadIdx.x & 63;
  const int row = (blockIdx.x * 256 + threadIdx.x) >> 6;
  float x0 = x[row * 2], x1 = x[row * 2 + 1];
#pragma unroll
  for (int q = 0; q < 4; ++q) {
    int e = l + q * 64;
    float v = fmaf(x0, W[e * 2], fmaf(x1, W[e * 2 + 1], b[e]));
    out[(size_t)row * NE + e] = __float2bfloat16(fmaxf(v, 0.f));
  }
}

__global__ void k_f2b(const float* __restrict__ in, bf16* __restrict__ out, int n) {
  int i = (blockIdx.x * 256 + threadIdx.x) * 4;
  if (i >= n) return;
  float4 v = *(const float4*)(in + i);
  out[i] = __float2bfloat16(v.x);
  out[i + 1] = __float2bfloat16(v.y);
  out[i + 2] = __float2bfloat16(v.z);
  out[i + 3] = __float2bfloat16(v.w);
}

__global__ void k_badd(const float* __restrict__ a, const float* __restrict__ b,
                       float* __restrict__ o, int n) {
  int i = blockIdx.x * 256 + threadIdx.x;
  if (i < n) o[i] = a[i] + b[i];
}

extern "C" void kernel_launch(void* const* d_in, const int* in_sizes, int n_in,
                              void* d_out, int out_size, void* d_ws, size_t ws_size,
                              hipStream_t stream) {
  const float* obs   = (const float*)d_in[0];
  const float* Wemb  = (const float*)d_in[1];
  const float* bemb  = (const float*)d_in[2];
  const float* Wih0f = (const float*)d_in[3];
  const float* Whh0f = (const float*)d_in[4];
  const float* bih0  = (const float*)d_in[5];
  const float* bhh0  = (const float*)d_in[6];
  const float* Wih1f = (const float*)d_in[7];
  const float* Whh1f = (const float*)d_in[8];
  const float* bih1  = (const float*)d_in[9];
  const float* bhh1  = (const float*)d_in[10];
  const float* W1f   = (const float*)d_in[11];
  const float* b1m   = (const float*)d_in[12];
  const float* W2    = (const float*)d_in[13];
  const float* b2    = (const float*)d_in[14];
  const float* W3    = (const float*)d_in[15];
  const float* b3    = (const float*)d_in[16];

  char* ws = (char*)d_ws;
  size_t off = 0;
  auto alloc = [&](size_t bytes) -> void* {
    void* p = ws + off;
    off += (bytes + 255) & ~(size_t)255;
    return p;
  };
  bf16* wih0 = (bf16*)alloc((size_t)4096 * 256 * 2);
  bf16* whh0 = (bf16*)alloc((size_t)4096 * 1024 * 2);
  bf16* wih1 = (bf16*)alloc((size_t)4096 * 1024 * 2);
  bf16* whh1 = (bf16*)alloc((size_t)4096 * 1024 * 2);
  bf16* w1b  = (bf16*)alloc((size_t)32 * 1024 * 2);
  float* b0c = (float*)alloc((size_t)4096 * 4);
  float* b1c = (float*)alloc((size_t)4096 * 4);
  bf16* emb  = (bf16*)alloc((size_t)8 * NB * NE * 2);
  bf16* h0a  = (bf16*)alloc((size_t)NB * NH * 2);
  bf16* h0b  = (bf16*)alloc((size_t)NB * NH * 2);
  bf16* h1a  = (bf16*)alloc((size_t)NB * NH * 2);
  bf16* h1b  = (bf16*)alloc((size_t)NB * NH * 2);
  float* c0  = (float*)alloc((size_t)NB * NH * 4);
  float* c1  = (float*)alloc((size_t)NB * NH * 4);
  float* curr = (float*)alloc((size_t)NB * 2 * 4);
  bf16* cemb = (bf16*)alloc((size_t)NB * NE * 2);

  k_f2b<<<1024, 256, 0, stream>>>(Wih0f, wih0, 4096 * 256);
  k_f2b<<<4096, 256, 0, stream>>>(Whh0f, whh0, 4096 * 1024);
  k_f2b<<<4096, 256, 0, stream>>>(Wih1f, wih1, 4096 * 1024);
  k_f2b<<<4096, 256, 0, stream>>>(Whh1f, whh1, 4096 * 1024);
  k_f2b<<<32, 256, 0, stream>>>(W1f, w1b, 32 * 1024);
  k_badd<<<16, 256, 0, stream>>>(bih0, bhh0, b0c, 4096);
  k_badd<<<16, 256, 0, stream>>>(bih1, bhh1, b1c, 4096);
  k_embed<<<(8 * NB) / 4, 256, 0, stream>>>(obs, Wemb, bemb, emb);

  bf16* h0buf[2] = {h0a, h0b};
  bf16* h1buf[2] = {h1a, h1b};
  float* preds = (float*)d_out;

  auto mk = [&](const bf16* X, int ldx, int Kx, const bf16* Hin, int Kh,
                const bf16* Wih, const bf16* Whh, const float* bb, float* C,
                bf16* Ho, int cz) {
    CellP q;
    q.X = X; q.Hin = Hin; q.Wih = Wih; q.Whh = Whh;
    q.bias = bb; q.Cst = C; q.Hout = Ho;
    q.ldx = ldx; q.Kx = Kx; q.Kh = Kh; q.czero = cz;
    return q;
  };

  // L0(0): encode step 0, h/c start at zero (Kh=0 -> Hin never read)
  {
    CellP p0 = mk(emb, NE, NE, h0buf[1], 0, wih0, whh0, b0c, c0, h0buf[0], 1);
    k_cell<<<512, 512, 0, stream>>>(p0, p0, 512);
  }
  // encode: fused L1(t) || L0(t+1), t = 0..7 (both depend only on h0(t))
  for (int t = 0; t < 8; ++t) {
    int cu = t & 1, pv = cu ^ 1;
    int kh1 = (t == 0) ? 0 : NH;
    CellP pl1 = mk(h0buf[cu], NH, NH, h1buf[pv], kh1,
                   wih1, whh1, b1c, c1, h1buf[cu], t == 0);
    const bf16* xnext = (t + 1 < 8) ? emb + (size_t)(t + 1) * NB * NE
                                    : emb + (size_t)7 * NB * NE;  // t+1==8: embed(obs[-1])
    CellP pl0 = mk(xnext, NE, NE, h0buf[cu], NH,
                   wih0, whh0, b0c, c0, h0buf[pv], 0);
    k_cell<<<1024, 512, 0, stream>>>(pl1, pl0, 512);
  }
  // decode: serial (L0 input comes from k_mlp of previous step)
  for (int t = 8; t < 20; ++t) {
    int cu = t & 1, pv = cu ^ 1;
    if (t > 8) {
      CellP pl0 = mk(cemb, NE, NE, h0buf[pv], NH,
                     wih0, whh0, b0c, c0, h0buf[cu], 0);
      k_cell<<<512, 512, 0, stream>>>(pl0, pl0, 512);
    }
    CellP pl1 = mk(h0buf[cu], NH, NH, h1buf[pv], NH,
                   wih1, whh1, b1c, c1, h1buf[cu], 0);
    k_cell<<<512, 512, 0, stream>>>(pl1, pl1, 512);
    int pI = t - 8;
    const float* cin = (pI == 0) ? (obs + (size_t)7 * NB * 2) : curr;
    k_mlp<<<NB / 4, 256, 0, stream>>>(h1buf[cu], w1b, b1m, W2, b2, W3, b3,
                                      cin, curr, preds + (size_t)pI * NB * 2,
                                      Wemb, bemb, cemb);
  }
}

// Round 15
// 4540.266 us; speedup vs baseline: 2.4630x; 1.0185x over previous
//
#include <hip/hip_runtime.h>
#include <hip/hip_bf16.h>
#include <stdint.h>

typedef __hip_bfloat16 bf16;
typedef __attribute__((ext_vector_type(8))) short bf16x8;
typedef __attribute__((ext_vector_type(4))) float f32x4;
typedef __attribute__((ext_vector_type(8))) unsigned short us8;

#define NB 8192
#define NE 256
#define NH 1024

__device__ __forceinline__ float bf2f(unsigned short u) {
  union { unsigned int i; float f; } x; x.i = ((unsigned int)u) << 16; return x.f;
}
__device__ __forceinline__ float sigm(float x) {
  return __builtin_amdgcn_rcpf(1.f + __expf(-x));
}
__device__ __forceinline__ float tanh_f(float x) {
  return 1.f - 2.f * __builtin_amdgcn_rcpf(1.f + __expf(2.f * x));
}

#define BAR() __builtin_amdgcn_s_barrier()
#define FENCE() asm volatile("" ::: "memory")
#define LGKME() asm volatile("s_waitcnt lgkmcnt(0)" ::: "memory")
#define VMW(N) asm volatile("s_waitcnt vmcnt(" #N ")" ::: "memory")

#define GLDS(G, S)                                                            \
  __builtin_amdgcn_global_load_lds(                                           \
      (const __attribute__((address_space(1))) void*)(G),                     \
      (__attribute__((address_space(3))) void*)(S), 16, 0, 0)

// 32-MFMA cluster. NO setprio: m190 measured setprio NEGATIVE on lockstep
// barrier-synced GEMM structures (T5 pays only with wave role-split).
#define MFMA32(MH)                                                            \
  do {                                                                        \
    _Pragma("unroll") for (int i_ = 0; i_ < 4; ++i_)                          \
      _Pragma("unroll") for (int g_ = 0; g_ < 4; ++g_) {                      \
        acc[(MH)*4 + i_][g_] = __builtin_amdgcn_mfma_f32_16x16x32_bf16(       \
            af[i_], bv[g_], acc[(MH)*4 + i_][g_], 0, 0, 0);                   \
        acc[(MH)*4 + i_][g_] = __builtin_amdgcn_mfma_f32_16x16x32_bf16(       \
            af[4 + i_], bv[4 + g_], acc[(MH)*4 + i_][g_], 0, 0, 0);           \
      }                                                                       \
  } while (0)

// ds_read A-frags: 4 m-frags of m-half MH, both k-slices (XOR-swizzled)
#define LDA8(BUF, MH)                                                         \
  do {                                                                        \
    const char* Ab_ = (const char*)&As[BUF][0][0];                            \
    _Pragma("unroll") for (int i_ = 0; i_ < 4; ++i_) {                        \
      int ro_ = (wr * 128 + (MH)*64 + i_ * 16 + l15) * 128;                   \
      af[i_]     = *(const bf16x8*)(Ab_ + ro_ + co0);                         \
      af[4 + i_] = *(const bf16x8*)(Ab_ + ro_ + co1);                         \
    }                                                                         \
  } while (0)

// ds_read B-frags: 4 gates, both k-slices
#define LDB8(BUF)                                                             \
  do {                                                                        \
    const char* Bb_ = (const char*)&Bs[BUF][0][0];                            \
    _Pragma("unroll") for (int g_ = 0; g_ < 4; ++g_) {                        \
      int ro_ = (g_ * 64 + nc * 16 + l15) * 128;                              \
      bv[g_]     = *(const bf16x8*)(Bb_ + ro_ + co0);                         \
      bv[4 + g_] = *(const bf16x8*)(Bb_ + ro_ + co1);                         \
    }                                                                         \
  } while (0)

struct CellP {
  const bf16* X; const bf16* Hin;
  const bf16* Wih; const bf16* Whh;
  const float* bias; float* Cst; bf16* Hout;
  int ldx, Kx, Kh, czero;
};

// -------- fused GEMM + LSTM cell, 256x256, 4-phase/iter (r12 champion) ------
// gates = X@Wih^T + Hin@Whh^T + bias ; c' = sig(f)*c + sig(i)*tanh(g); h = sig(o)*tanh(c')
// Block: 256 M-rows x (64 hcols x 4 gates). 8 waves (2M x 4N), wave = 128x64.
// Phase: {ds_read; stage; BAR; MFMA (compiler-progressive lgkm waits);
//         lgkmcnt(0); (VMW); BAR}.
// Register invariant: acc = 128 AGPR; arch VGPRs must stay <= ~116 (cap 128
// at 2 waves/SIMD) -> staging math stays per-call (hoisting spills, r14).
__global__ __launch_bounds__(512, 2) void k_cell(CellP PA, CellP PB, int nA)
{
  __shared__ bf16 As[2][256][64];
  __shared__ bf16 Bs[2][256][64];

  const CellP p = (blockIdx.x < (unsigned)nA) ? PA : PB;
  const int bid = (blockIdx.x < (unsigned)nA) ? blockIdx.x : (blockIdx.x - nA);

  const int tid = threadIdx.x;
  const int l = tid & 63;
  const int l15 = l & 15;
  const int wv = tid >> 6;
  const int wr = wv >> 2;
  const int nc = wv & 3;

  // m-major XCD ownership: XCD x owns m-tiles {4x..4x+3} x all hc (L2-fit A).
  const int xcd = bid & 7, j = bid >> 3;
  const int m0 = (xcd * 4 + (j & 3)) * 256;
  const int hc0 = (j >> 2) * 64;

  const int NT = (p.Kx + p.Kh) >> 6;
  const int T = NT >> 1;
  const int Kx = p.Kx;

  const int rowid = tid >> 3;
  const int ch8 = ((tid & 7) ^ (rowid & 7)) * 8;
  const int wv8 = wv * 8;

  const int co0 = (((l >> 4) + 0) ^ (l & 7)) * 16;
  const int co1 = (((l >> 4) + 4) ^ (l & 7)) * 16;

  f32x4 acc[8][4];
  f32x4 zero4 = {0.f, 0.f, 0.f, 0.f};
#pragma unroll
  for (int i = 0; i < 8; ++i)
#pragma unroll
    for (int j2 = 0; j2 < 4; ++j2) acc[i][j2] = zero4;

  // 32-bit address math: (m0+tr+rowid)*ld <= 8192*2048 = 16.7M < 2^31.
  auto stage_a = [&](int buf, int half, int kt) {
    int kc = kt << 6;
    const bf16* src; int ldi;
    if (kc < Kx) { src = p.X + kc; ldi = p.ldx; }
    else         { src = p.Hin + (kc - Kx); ldi = NH; }
#pragma unroll
    for (int rnd = 0; rnd < 2; ++rnd) {
      int tr = rnd * 128 + half * 64;
      const bf16* gp = src + (unsigned)((m0 + tr + rowid) * ldi + ch8);
      GLDS(gp, &As[buf][tr + wv8][0]);
    }
  };
  auto stage_b = [&](int buf, int half, int kt) {
    int kc = kt << 6;
    const bf16* src; int ldi;
    if (kc < Kx) { src = p.Wih + kc; ldi = Kx; }
    else         { src = p.Whh + (kc - Kx); ldi = NH; }
#pragma unroll
    for (int rnd = 0; rnd < 2; ++rnd) {
      int gate = rnd * 2 + half;
      const bf16* gp = src + (unsigned)((gate * NH + hc0 + rowid) * ldi + ch8);
      GLDS(gp, &Bs[buf][gate * 64 + wv8][0]);
    }
  };

  // prologue: full b0(kt0) + A1.h0(kt1)
  stage_a(0, 0, 0);
  stage_a(0, 1, 0);
  stage_b(0, 0, 0);
  stage_b(0, 1, 0);
  stage_a(1, 0, 1);
  VMW(2);
  BAR();

  for (int t = 0; t < T; ++t) {
    const int kt1 = 2 * t + 1;
    const bool last = (t == T - 1);
    bf16x8 af[8], bv[8];

    // Ph1: compute b0.mh0 ; stage A1.h1 + B1 (kt1)
    LDB8(0); LDA8(0, 0);
    stage_a(1, 1, kt1);
    stage_b(1, 0, kt1);
    stage_b(1, 1, kt1);
    FENCE(); BAR();
    MFMA32(0);
    LGKME();
    BAR();

    // Ph2: compute b0.mh1 ; stage A0.h0 (kt0+2)
    LDA8(0, 1);
    if (!last) stage_a(0, 0, kt1 + 1);
    FENCE(); BAR();
    MFMA32(1);
    LGKME();
    if (last) { VMW(0); } else { VMW(2); }  // complete b1(kt1); leave A0.h0
    BAR();

    // Ph3: compute b1.mh0 ; stage A0.h1 + B0 (kt0+2)
    LDB8(1); LDA8(1, 0);
    if (!last) {
      stage_a(0, 1, kt1 + 1);
      stage_b(0, 0, kt1 + 1);
      stage_b(0, 1, kt1 + 1);
    }
    FENCE(); BAR();
    MFMA32(0);
    LGKME();
    BAR();

    // Ph4: compute b1.mh1 ; stage A1.h0 (kt1+2)
    LDA8(1, 1);
    if (!last) stage_a(1, 0, kt1 + 2);
    FENCE(); BAR();
    MFMA32(1);
    LGKME();
    if (!last) { VMW(2); }  // complete b0(kt0+2); leave A1.h0(kt1+2)
    BAR();
  }

  // epilogue: acc[m][gate][r]; C/D layout col=lane&15, row=(lane>>4)*4+r
  const int ecol = hc0 + nc * 16 + l15;
  const float bi = p.bias[ecol];
  const float bff = p.bias[NH + ecol];
  const float bg = p.bias[2 * NH + ecol];
  const float bo = p.bias[3 * NH + ecol];
  const int r0 = m0 + wr * 128 + ((l >> 4) << 2);
#pragma unroll
  for (int m = 0; m < 8; ++m) {
#pragma unroll
    for (int r = 0; r < 4; ++r) {
      int row = r0 + m * 16 + r;
      unsigned idx = (unsigned)(row * NH) + ecol;   // <= 8.39M, 32-bit safe
      float gi = sigm(acc[m][0][r] + bi);
      float gf = sigm(acc[m][1][r] + bff);
      float gg = tanh_f(acc[m][2][r] + bg);
      float go = sigm(acc[m][3][r] + bo);
      float cold = p.czero ? 0.f : p.Cst[idx];
      float cn = gf * cold + gi * gg;
      p.Cst[idx] = cn;
      p.Hout[idx] = __float2bfloat16(go * tanh_f(cn));
    }
  }
}

// ---------------- MLP decode head + displacement add + re-embed ----------------
__global__ __launch_bounds__(256) void k_mlp(
    const bf16* __restrict__ h1, const bf16* __restrict__ W1b, const float* __restrict__ b1,
    const float* __restrict__ W2, const float* __restrict__ b2,
    const float* __restrict__ W3, const float* __restrict__ b3,
    const float* __restrict__ cin, float* __restrict__ cout,
    float* __restrict__ preds, const float* __restrict__ Wemb,
    const float* __restrict__ bemb, bf16* __restrict__ embout)
{
  const int l = threadIdx.x & 63;
  const int row = blockIdx.x * 4 + (threadIdx.x >> 6);

  const us8* hp = (const us8*)(h1 + (size_t)row * NH + l * 16);
  us8 hv0 = hp[0], hv1 = hp[1];
  float h[16];
#pragma unroll
  for (int j = 0; j < 8; ++j) { h[j] = bf2f(hv0[j]); h[8 + j] = bf2f(hv1[j]); }

  float y1[32];
#pragma unroll
  for (int j = 0; j < 32; ++j) {
    const us8* wp = (const us8*)(W1b + (size_t)j * NH + l * 16);
    us8 w0 = wp[0], w1 = wp[1];
    float d = 0.f;
#pragma unroll
    for (int k = 0; k < 8; ++k) {
      d = fmaf(h[k], bf2f(w0[k]), d);
      d = fmaf(h[8 + k], bf2f(w1[k]), d);
    }
#pragma unroll
    for (int off2 = 32; off2 > 0; off2 >>= 1) d += __shfl_xor(d, off2);
    y1[j] = fmaxf(d + b1[j], 0.f);
  }

  float y2[16];
#pragma unroll
  for (int m = 0; m < 16; ++m) {
    float s = b2[m];
#pragma unroll
    for (int j = 0; j < 32; ++j) s = fmaf(W2[m * 32 + j], y1[j], s);
    y2[m] = fmaxf(s, 0.f);
  }
  float o0 = b3[0], o1 = b3[1];
#pragma unroll
  for (int k = 0; k < 16; ++k) {
    o0 = fmaf(W3[k], y2[k], o0);
    o1 = fmaf(W3[16 + k], y2[k], o1);
  }
  float n0 = cin[row * 2] + o0;
  float n1 = cin[row * 2 + 1] + o1;
  if (l == 0) {
    preds[row * 2] = n0; preds[row * 2 + 1] = n1;
    cout[row * 2] = n0;  cout[row * 2 + 1] = n1;
  }
#pragma unroll
  for (int q = 0; q < 4; ++q) {
    int e = l + q * 64;
    float v = fmaf(n0, Wemb[e * 2], fmaf(n1, Wemb[e * 2 + 1], bemb[e]));
    embout[(size_t)row * NE + e] = __float2bfloat16(fmaxf(v, 0.f));
  }
}

// ---------------- embedding of observed trajectory (all 8 steps) ----------------
__global__ void k_embed(const float* __restrict__ x, const float* __restrict__ W,
                        const float* __restrict__ b, bf16* __restrict__ out) {
  const int l = threadIdx.x & 63;
  const int row = (blockIdx.x * 256 + threadIdx.x) >> 6;
  float x0 = x[row * 2], x1 = x[row * 2 + 1];
#pragma unroll
  for (int q = 0; q < 4; ++q) {
    int e = l + q * 64;
    float v = fmaf(x0, W[e * 2], fmaf(x1, W[e * 2 + 1], b[e]));
    out[(size_t)row * NE + e] = __float2bfloat16(fmaxf(v, 0.f));
  }
}

__global__ void k_f2b(const float* __restrict__ in, bf16* __restrict__ out, int n) {
  int i = (blockIdx.x * 256 + threadIdx.x) * 4;
  if (i >= n) return;
  float4 v = *(const float4*)(in + i);
  out[i] = __float2bfloat16(v.x);
  out[i + 1] = __float2bfloat16(v.y);
  out[i + 2] = __float2bfloat16(v.z);
  out[i + 3] = __float2bfloat16(v.w);
}

__global__ void k_badd(const float* __restrict__ a, const float* __restrict__ b,
                       float* __restrict__ o, int n) {
  int i = blockIdx.x * 256 + threadIdx.x;
  if (i < n) o[i] = a[i] + b[i];
}

extern "C" void kernel_launch(void* const* d_in, const int* in_sizes, int n_in,
                              void* d_out, int out_size, void* d_ws, size_t ws_size,
                              hipStream_t stream) {
  const float* obs   = (const float*)d_in[0];
  const float* Wemb  = (const float*)d_in[1];
  const float* bemb  = (const float*)d_in[2];
  const float* Wih0f = (const float*)d_in[3];
  const float* Whh0f = (const float*)d_in[4];
  const float* bih0  = (const float*)d_in[5];
  const float* bhh0  = (const float*)d_in[6];
  const float* Wih1f = (const float*)d_in[7];
  const float* Whh1f = (const float*)d_in[8];
  const float* bih1  = (const float*)d_in[9];
  const float* bhh1  = (const float*)d_in[10];
  const float* W1f   = (const float*)d_in[11];
  const float* b1m   = (const float*)d_in[12];
  const float* W2    = (const float*)d_in[13];
  const float* b2    = (const float*)d_in[14];
  const float* W3    = (const float*)d_in[15];
  const float* b3    = (const float*)d_in[16];

  char* ws = (char*)d_ws;
  size_t off = 0;
  auto alloc = [&](size_t bytes) -> void* {
    void* p = ws + off;
    off += (bytes + 255) & ~(size_t)255;
    return p;
  };
  bf16* wih0 = (bf16*)alloc((size_t)4096 * 256 * 2);
  bf16* whh0 = (bf16*)alloc((size_t)4096 * 1024 * 2);
  bf16* wih1 = (bf16*)alloc((size_t)4096 * 1024 * 2);
  bf16* whh1 = (bf16*)alloc((size_t)4096 * 1024 * 2);
  bf16* w1b  = (bf16*)alloc((size_t)32 * 1024 * 2);
  float* b0c = (float*)alloc((size_t)4096 * 4);
  float* b1c = (float*)alloc((size_t)4096 * 4);
  bf16* emb  = (bf16*)alloc((size_t)8 * NB * NE * 2);
  bf16* h0a  = (bf16*)alloc((size_t)NB * NH * 2);
  bf16* h0b  = (bf16*)alloc((size_t)NB * NH * 2);
  bf16* h1a  = (bf16*)alloc((size_t)NB * NH * 2);
  bf16* h1b  = (bf16*)alloc((size_t)NB * NH * 2);
  float* c0  = (float*)alloc((size_t)NB * NH * 4);
  float* c1  = (float*)alloc((size_t)NB * NH * 4);
  float* curr = (float*)alloc((size_t)NB * 2 * 4);
  bf16* cemb = (bf16*)alloc((size_t)NB * NE * 2);

  k_f2b<<<1024, 256, 0, stream>>>(Wih0f, wih0, 4096 * 256);
  k_f2b<<<4096, 256, 0, stream>>>(Whh0f, whh0, 4096 * 1024);
  k_f2b<<<4096, 256, 0, stream>>>(Wih1f, wih1, 4096 * 1024);
  k_f2b<<<4096, 256, 0, stream>>>(Whh1f, whh1, 4096 * 1024);
  k_f2b<<<32, 256, 0, stream>>>(W1f, w1b, 32 * 1024);
  k_badd<<<16, 256, 0, stream>>>(bih0, bhh0, b0c, 4096);
  k_badd<<<16, 256, 0, stream>>>(bih1, bhh1, b1c, 4096);
  k_embed<<<(8 * NB) / 4, 256, 0, stream>>>(obs, Wemb, bemb, emb);

  bf16* h0buf[2] = {h0a, h0b};
  bf16* h1buf[2] = {h1a, h1b};
  float* preds = (float*)d_out;

  auto mk = [&](const bf16* X, int ldx, int Kx, const bf16* Hin, int Kh,
                const bf16* Wih, const bf16* Whh, const float* bb, float* C,
                bf16* Ho, int cz) {
    CellP q;
    q.X = X; q.Hin = Hin; q.Wih = Wih; q.Whh = Whh;
    q.bias = bb; q.Cst = C; q.Hout = Ho;
    q.ldx = ldx; q.Kx = Kx; q.Kh = Kh; q.czero = cz;
    return q;
  };

  // L0(0): encode step 0, h/c start at zero (Kh=0 -> Hin never read)
  {
    CellP p0 = mk(emb, NE, NE, h0buf[1], 0, wih0, whh0, b0c, c0, h0buf[0], 1);
    k_cell<<<512, 512, 0, stream>>>(p0, p0, 512);
  }
  // encode: fused L1(t) || L0(t+1), t = 0..7 (both depend only on h0(t))
  for (int t = 0; t < 8; ++t) {
    int cu = t & 1, pv = cu ^ 1;
    int kh1 = (t == 0) ? 0 : NH;
    CellP pl1 = mk(h0buf[cu], NH, NH, h1buf[pv], kh1,
                   wih1, whh1, b1c, c1, h1buf[cu], t == 0);
    const bf16* xnext = (t + 1 < 8) ? emb + (size_t)(t + 1) * NB * NE
                                    : emb + (size_t)7 * NB * NE;  // t+1==8: embed(obs[-1])
    CellP pl0 = mk(xnext, NE, NE, h0buf[cu], NH,
                   wih0, whh0, b0c, c0, h0buf[pv], 0);
    k_cell<<<1024, 512, 0, stream>>>(pl1, pl0, 512);
  }
  // decode: serial (L0 input comes from k_mlp of previous step)
  for (int t = 8; t < 20; ++t) {
    int cu = t & 1, pv = cu ^ 1;
    if (t > 8) {
      CellP pl0 = mk(cemb, NE, NE, h0buf[pv], NH,
                     wih0, whh0, b0c, c0, h0buf[cu], 0);
      k_cell<<<512, 512, 0, stream>>>(pl0, pl0, 512);
    }
    CellP pl1 = mk(h0buf[cu], NH, NH, h1buf[pv], NH,
                   wih1, whh1, b1c, c1, h1buf[cu], 0);
    k_cell<<<512, 512, 0, stream>>>(pl1, pl1, 512);
    int pI = t - 8;
    const float* cin = (pI == 0) ? (obs + (size_t)7 * NB * 2) : curr;
    k_mlp<<<NB / 4, 256, 0, stream>>>(h1buf[cu], w1b, b1m, W2, b2, W3, b3,
                                      cin, curr, preds + (size_t)pI * NB * 2,
                                      Wemb, bemb, cemb);
  }
}